// Round 1
// baseline (88.131 us; speedup 1.0000x reference)
//
#include <hip/hip_runtime.h>

#define L_LEN 4096
#define NT 1024
#define ROWS 512               // B*J = 32*16 fixed by the reference
#define SLOP 48u               // f32-key error band (actual error <= ~4 ulps; 12x margin)
#define BCAP 256

// Round 11: single-axis change vs the 87.26-us re-anchor: NT 512 -> 1024
// (4 elems/thread instead of 8). Grid stays 512 (1 block/row), so occupancy
// goes 16 -> 32 waves/CU (grid was the limiter, VGPR=20). Algorithm is
// byte-identical: f32 keys r = max(w,1e-30)/(-ln u), 12+8-bit radix
// localization, SLOP-band exact f64 refine, same outputs.
// Do NOT reapply the round-9/10 restructures (fused hist+logf, hoisted loads,
// in-branch barriers, cnt-from-hist) — they triggered a codegen cliff.
__global__ __launch_bounds__(NT, 8) void AttentionEssentialReinforce_51238959841470_kernel(
    const int* __restrict__ ids,       // int32 OR little-endian int64 (auto-detected)
    const float* __restrict__ amask,   // (ROWS, 2*L), only first half used
    const float* __restrict__ uin,     // (ROWS, L)
    float* __restrict__ out,           // float32: [ids | mask | -mask], n_per each
    int n_per)
{
    __shared__ unsigned int hist[4096];          // 16 KB (pass 0: 12-bit bins)
    __shared__ unsigned int s_wtot[16], s_woff[16];
    __shared__ unsigned long long bkey[BCAP];    // band: exact f64 keys
    __shared__ int bidx[BCAP];                   // band: element indices
    __shared__ unsigned int s_cnt, s_or, s_remk, s_prefix, s_nhi, s_bn;

    const int row = blockIdx.x;
    const int tid = threadIdx.x;
    const int lane = tid & 63, wid = tid >> 6;
    const float* wrow = amask + (size_t)row * (2 * L_LEN);
    const float* urow = uin + (size_t)row * L_LEN;

    if (tid == 0) { s_cnt = 0; s_or = 0; s_nhi = 0; s_bn = 0; }
    __syncthreads();

    // int64-vs-int32 id detection: LE int64 ids (<2^31) have all-zero odd words.
    if (((const unsigned*)ids)[2 * tid + 1] != 0u) s_or = 1u;   // benign race

    // ---- Phase 1: f32 keys in registers. r = max(w,1e-30)/(-ln u) is monotone-
    // equivalent to log(max(w,1e-30))+gumbel(u); positive-float IEEE bits are
    // order-isomorphic to value. (u==1 -> r=+inf-like top key, matching reference.)
    float wv[4], uv[4];
    {
        float4 a0 = reinterpret_cast<const float4*>(wrow)[tid];
        float4 b0 = reinterpret_cast<const float4*>(urow)[tid];
        wv[0]=a0.x; wv[1]=a0.y; wv[2]=a0.z; wv[3]=a0.w;
        uv[0]=b0.x; uv[1]=b0.y; uv[2]=b0.z; uv[3]=b0.w;
    }
    unsigned key[4];
    unsigned localnz = 0;
    #pragma unroll
    for (int e = 0; e < 4; ++e) {
        key[e] = 0u;                                  // w<=0 -> bottom, never selected
        if (wv[e] > 0.0f) {
            float t = -logf(uv[e]);
            float r = fmaxf(wv[e], 1e-30f) / t;
            key[e] = __float_as_uint(r);
            localnz++;
        }
    }
    unsigned v = localnz;
    #pragma unroll
    for (int off = 32; off > 0; off >>= 1) v += __shfl_down(v, off, 64);
    if (lane == 0) atomicAdd(&s_cnt, v);
    __syncthreads();

    const bool is64 = (s_or == 0u);
    const int cnt = (int)s_cnt;
    const int k = (int)floorf(0.15f * (float)cnt);    // f32(0.15)*f32(cnt), floored (as np)

    // Prefetch ids now: L2 latency overlaps the radix passes below.
    int ida[4];
    if (!is64) {
        int4 t0 = reinterpret_cast<const int4*>(ids + (size_t)row * L_LEN)[tid];
        ida[0]=t0.x; ida[1]=t0.y; ida[2]=t0.z; ida[3]=t0.w;
    } else {
        const longlong2* idr = reinterpret_cast<const longlong2*>(
            (const long long*)ids + (size_t)row * L_LEN);
        longlong2 a = idr[2 * tid], b = idr[2 * tid + 1];
        ida[0]=(int)a.x; ida[1]=(int)a.y; ida[2]=(int)b.x; ida[3]=(int)b.y;
    }

    unsigned lo_thr = 0xFFFFFFFFu, hi_thr = 0xFFFFFFFFu;   // k==0: select none
    int need = 0;
    unsigned bn = 0;

    if (k > 0) {
        // ---- Phase 2: localize the k-th largest f32 key to its 20-bit-prefix bin.
        // Pass 0: 12-bit field (bits 31:20), 4096 bins.
        for (int b = tid; b < 4096; b += NT) hist[b] = 0;
        __syncthreads();
        #pragma unroll
        for (int e = 0; e < 4; ++e) atomicAdd(&hist[key[e] >> 20], 1u);
        __syncthreads();
        {
            int b0 = 4095 - 4 * tid;                 // 4 descending bins per thread
            unsigned c[4], lsum = 0;
            #pragma unroll
            for (int m = 0; m < 4; ++m) { c[m] = hist[b0 - m]; lsum += c[m]; }
            unsigned scan = lsum;
            #pragma unroll
            for (int off = 1; off < 64; off <<= 1) {
                unsigned o = __shfl_up(scan, (unsigned)off, 64);
                if (lane >= off) scan += o;
            }
            if (lane == 63) s_wtot[wid] = scan;
            __syncthreads();
            if (tid < 16) {
                unsigned acc = 0;
                for (int w2 = 0; w2 < tid; ++w2) acc += s_wtot[w2];
                s_woff[tid] = acc;
            }
            __syncthreads();
            unsigned run = s_woff[wid] + (scan - lsum);   // count in strictly-higher bins
            unsigned remk = (unsigned)k;
            #pragma unroll
            for (int m = 0; m < 4; ++m) {
                if (run < remk && run + c[m] >= remk) {   // exactly one (thread,m) hits
                    s_prefix = (unsigned)(b0 - m);
                    s_remk = remk - run;
                }
                run += c[m];
            }
        }
        __syncthreads();
        unsigned prefix12 = s_prefix;
        unsigned remk = s_remk;

        // Pass 1: 8-bit field (bits 19:12), 256 bins, keys matching prefix12 only.
        if (tid < 256) hist[tid] = 0;
        __syncthreads();
        #pragma unroll
        for (int e = 0; e < 4; ++e)
            if ((key[e] >> 20) == prefix12)
                atomicAdd(&hist[(key[e] >> 12) & 0xFFu], 1u);
        __syncthreads();
        if (tid < 64) {                              // wave 0: descending-bin scan
            unsigned c[4], lsum = 0;
            #pragma unroll
            for (int m = 0; m < 4; ++m) { c[m] = hist[255 - 4 * tid - m]; lsum += c[m]; }
            unsigned scan = lsum;
            #pragma unroll
            for (int off = 1; off < 64; off <<= 1) {
                unsigned o = __shfl_up(scan, (unsigned)off, 64);
                if (tid >= off) scan += o;
            }
            unsigned run = scan - lsum;
            #pragma unroll
            for (int m = 0; m < 4; ++m) {
                if (run < remk && run + c[m] >= remk) {
                    s_prefix = (prefix12 << 8) | (unsigned)(255 - 4 * tid - m);
                }
                run += c[m];
            }
        }
        __syncthreads();
        const unsigned T20 = s_prefix;               // k-th key's 20-bit prefix
        const unsigned B_lo = T20 << 12, B_hi = (T20 << 12) | 0xFFFu;

        // ---- Error band: [B_lo - SLOP, B_hi + SLOP]. key > hi => certainly top-k;
        // key < lo => certainly not; band resolved exactly in f64 below.
        lo_thr = (B_lo > SLOP) ? B_lo - SLOP : 1u;   // >=1 excludes w<=0 sentinels
        hi_thr = B_hi + SLOP;                        // no overflow (keys <= 0x7F800000)
        unsigned nhi = 0;
        #pragma unroll
        for (int e = 0; e < 4; ++e) {
            if (key[e] > hi_thr) {
                nhi++;
            } else if (key[e] >= lo_thr) {
                unsigned pos = atomicAdd(&s_bn, 1u);
                if (pos < BCAP) {
                    double t = -log((double)uv[e]);
                    double r = (double)fmaxf(wv[e], 1e-30f) / t;   // exact-order key
                    bkey[pos] = (unsigned long long)__double_as_longlong(r);
                    bidx[pos] = 4 * tid + e;
                }
            }
        }
        unsigned nv = nhi;
        #pragma unroll
        for (int off = 32; off > 0; off >>= 1) nv += __shfl_down(nv, off, 64);
        if (lane == 0) atomicAdd(&s_nhi, nv);
        __syncthreads();
        need = k - (int)s_nhi;                       // >= 1; bn >= need by construction
        bn = s_bn; if (bn > BCAP) bn = BCAP;
    }

    // ---- Phase 3: selection + float32 outputs ----
    const size_t obase = (size_t)row * L_LEN;
    float* o0 = out + obase;                      // masked ids
    float* o1 = out + (size_t)n_per + obase;      // mask
    float* o2 = out + 2 * (size_t)n_per + obase;  // -mask

    float f0[4], f1[4], f2[4];
    #pragma unroll
    for (int e = 0; e < 4; ++e) {
        bool sel;
        if (key[e] > hi_thr) {
            sel = true;
        } else if (key[e] < lo_thr) {
            sel = false;
        } else {
            // band member: rank by (f64 key desc, index asc) — stable, exact
            double t = -log((double)uv[e]);
            double r = (double)fmaxf(wv[e], 1e-30f) / t;
            unsigned long long myk = (unsigned long long)__double_as_longlong(r);
            int myi = 4 * tid + e;
            int rnk = 0;
            for (unsigned j = 0; j < bn; ++j)
                rnk += (bkey[j] > myk) || (bkey[j] == myk && bidx[j] < myi);
            sel = (rnk < need);
        }
        f0[e] = sel ? 103.0f : (float)ida[e];
        f1[e] = sel ? 1.0f : 0.0f;
        f2[e] = sel ? -1.0f : -0.0f;
    }
    reinterpret_cast<float4*>(o0)[tid] = make_float4(f0[0], f0[1], f0[2], f0[3]);
    reinterpret_cast<float4*>(o1)[tid] = make_float4(f1[0], f1[1], f1[2], f1[3]);
    reinterpret_cast<float4*>(o2)[tid] = make_float4(f2[0], f2[1], f2[2], f2[3]);
}

extern "C" void kernel_launch(void* const* d_in, const int* in_sizes, int n_in,
                              void* d_out, int out_size, void* d_ws, size_t ws_size,
                              hipStream_t stream) {
    const int*   ids   = (const int*)d_in[0];     // (B,J,L) ids (int32/int64 auto-detect)
    const float* amask = (const float*)d_in[1];   // (B,J,2L) float32
    const float* uin   = (const float*)d_in[2];   // (B,J,L) float32
    float* out = (float*)d_out;                   // float32 x (3 * B*J*L)

    const int n_per = ROWS * L_LEN;               // 2,097,152 (hardcoded geometry)

    AttentionEssentialReinforce_51238959841470_kernel<<<dim3(ROWS), dim3(NT), 0, stream>>>(
        ids, amask, uin, out, n_per);
}

// Round 2
// 86.981 us; speedup vs baseline: 1.0132x; 1.0132x over previous
//
#include <hip/hip_runtime.h>

#define L_LEN 4096
#define NT 1024
#define ROWS 512               // B*J = 32*16 fixed by the reference
#define SLOP 48u               // f32-key error band (actual error <= ~4 ulps; 12x margin)
#define BCAP 256
#define NW (NT / 64)           // 16 waves

// Round 12: barrier-diet vs the round-11 kernel (NT=1024, neutral vs anchor).
// Three deltas, all serialization-removal, phase structure unchanged:
//  (a) hist[4096] + h2[256] zeroed right after the global loads are ISSUED
//      (hides under HBM latency); h2 is a dedicated pass-1 array so the
//      "if(tid<256) hist[tid]=0" + barrier pair is gone.
//  (b) s_cnt / s_or / s_nhi shared atomics -> per-wave lane-0 writes into
//      16-entry arrays, summed by every thread after an existing barrier.
//      Removes the tid==0 init + barrier B1 entirely.
//  (c) s_woff serial (tid<16) step -> each thread inlines the 15-element
//      prefix sum of s_wtot. Removes one barrier.
// Barriers: 11 -> 7. Key math, radix passes, SLOP band, outputs: unchanged.
// NOT reapplied (round-9/10 cliff): hist+logf fusion, cnt-from-hist,
// id-load hoisting.
__global__ __launch_bounds__(NT, 8) void AttentionEssentialReinforce_51238959841470_kernel(
    const int* __restrict__ ids,       // int32 OR little-endian int64 (auto-detected)
    const float* __restrict__ amask,   // (ROWS, 2*L), only first half used
    const float* __restrict__ uin,     // (ROWS, L)
    float* __restrict__ out,           // float32: [ids | mask | -mask], n_per each
    int n_per)
{
    __shared__ unsigned int hist[4096];          // 16 KB (pass 0: 12-bit bins)
    __shared__ unsigned int h2[256];             // pass 1 bins (pre-zeroed early)
    __shared__ unsigned int s_cntw[NW], s_orw[NW], s_nhiw[NW], s_wtot[NW];
    __shared__ unsigned long long bkey[BCAP];    // band: exact f64 keys
    __shared__ int bidx[BCAP];                   // band: element indices
    __shared__ unsigned int s_remk, s_prefix, s_bn;

    const int row = blockIdx.x;
    const int tid = threadIdx.x;
    const int lane = tid & 63, wid = tid >> 6;
    const float* wrow = amask + (size_t)row * (2 * L_LEN);
    const float* urow = uin + (size_t)row * L_LEN;

    // ---- Issue the hot loads first; everything below overlaps their latency.
    float4 a0 = reinterpret_cast<const float4*>(wrow)[tid];
    float4 b0 = reinterpret_cast<const float4*>(urow)[tid];
    // int64-vs-int32 id detection: LE int64 ids (<2^31) have all-zero odd words.
    unsigned odd = ((const unsigned*)ids)[2 * tid + 1];

    // Zero histograms while the loads are in flight (off the critical path).
    #pragma unroll
    for (int b = 0; b < 4096 / NT; ++b) hist[tid + b * NT] = 0u;
    if (tid < 256) h2[tid] = 0u;
    if (tid == 0) s_bn = 0u;

    // ---- Phase 1: f32 keys in registers. r = max(w,1e-30)/(-ln u) is monotone-
    // equivalent to log(max(w,1e-30))+gumbel(u); positive-float IEEE bits are
    // order-isomorphic to value. (u==1 -> r=+inf-like top key, matching reference.)
    float wv[4], uv[4];
    wv[0]=a0.x; wv[1]=a0.y; wv[2]=a0.z; wv[3]=a0.w;
    uv[0]=b0.x; uv[1]=b0.y; uv[2]=b0.z; uv[3]=b0.w;

    unsigned key[4];
    unsigned localnz = 0;
    #pragma unroll
    for (int e = 0; e < 4; ++e) {
        key[e] = 0u;                                  // w<=0 -> bottom, never selected
        if (wv[e] > 0.0f) {
            float t = -logf(uv[e]);
            float r = fmaxf(wv[e], 1e-30f) / t;
            key[e] = __float_as_uint(r);
            localnz++;
        }
    }
    {
        unsigned long long bal = __ballot(odd != 0u);
        unsigned v = localnz;
        #pragma unroll
        for (int off = 32; off > 0; off >>= 1) v += __shfl_down(v, off, 64);
        if (lane == 0) { s_cntw[wid] = v; s_orw[wid] = (bal != 0ull) ? 1u : 0u; }
    }
    __syncthreads();                                  // covers keys' wave sums + zeroing

    unsigned cnt = 0, orr = 0;
    #pragma unroll
    for (int w2 = 0; w2 < NW; ++w2) { cnt += s_cntw[w2]; orr |= s_orw[w2]; }
    const bool is64 = (orr == 0u);
    const int k = (int)floorf(0.15f * (float)cnt);    // f32(0.15)*f32(cnt), floored (as np)

    // Prefetch ids now: L2 latency overlaps the radix passes below.
    int ida[4];
    if (!is64) {
        int4 t0 = reinterpret_cast<const int4*>(ids + (size_t)row * L_LEN)[tid];
        ida[0]=t0.x; ida[1]=t0.y; ida[2]=t0.z; ida[3]=t0.w;
    } else {
        const longlong2* idr = reinterpret_cast<const longlong2*>(
            (const long long*)ids + (size_t)row * L_LEN);
        longlong2 a = idr[2 * tid], b = idr[2 * tid + 1];
        ida[0]=(int)a.x; ida[1]=(int)a.y; ida[2]=(int)b.x; ida[3]=(int)b.y;
    }

    unsigned lo_thr = 0xFFFFFFFFu, hi_thr = 0xFFFFFFFFu;   // k==0: select none
    int need = 0;
    unsigned bn = 0;

    if (k > 0) {
        // ---- Phase 2: localize the k-th largest f32 key to its 20-bit-prefix bin.
        // Pass 0: 12-bit field (bits 31:20), 4096 bins (pre-zeroed above).
        #pragma unroll
        for (int e = 0; e < 4; ++e) atomicAdd(&hist[key[e] >> 20], 1u);
        __syncthreads();
        {
            int b0i = 4095 - 4 * tid;                // 4 descending bins per thread
            unsigned c[4], lsum = 0;
            #pragma unroll
            for (int m = 0; m < 4; ++m) { c[m] = hist[b0i - m]; lsum += c[m]; }
            unsigned scan = lsum;
            #pragma unroll
            for (int off = 1; off < 64; off <<= 1) {
                unsigned o = __shfl_up(scan, (unsigned)off, 64);
                if (lane >= off) scan += o;
            }
            if (lane == 63) s_wtot[wid] = scan;
            __syncthreads();
            unsigned woff = 0;                       // inline cross-wave prefix (no barrier)
            #pragma unroll
            for (int w2 = 0; w2 < NW; ++w2) woff += (w2 < wid) ? s_wtot[w2] : 0u;
            unsigned run = woff + (scan - lsum);     // count in strictly-higher bins
            unsigned remk = (unsigned)k;
            #pragma unroll
            for (int m = 0; m < 4; ++m) {
                if (run < remk && run + c[m] >= remk) {   // exactly one (thread,m) hits
                    s_prefix = (unsigned)(b0i - m);
                    s_remk = remk - run;
                }
                run += c[m];
            }
        }
        __syncthreads();
        unsigned prefix12 = s_prefix;
        unsigned remk = s_remk;

        // Pass 1: 8-bit field (bits 19:12), 256 bins (h2, pre-zeroed), matching keys only.
        #pragma unroll
        for (int e = 0; e < 4; ++e)
            if ((key[e] >> 20) == prefix12)
                atomicAdd(&h2[(key[e] >> 12) & 0xFFu], 1u);
        __syncthreads();
        if (tid < 64) {                              // wave 0: descending-bin scan
            unsigned c[4], lsum = 0;
            #pragma unroll
            for (int m = 0; m < 4; ++m) { c[m] = h2[255 - 4 * tid - m]; lsum += c[m]; }
            unsigned scan = lsum;
            #pragma unroll
            for (int off = 1; off < 64; off <<= 1) {
                unsigned o = __shfl_up(scan, (unsigned)off, 64);
                if (tid >= off) scan += o;
            }
            unsigned run = scan - lsum;
            #pragma unroll
            for (int m = 0; m < 4; ++m) {
                if (run < remk && run + c[m] >= remk) {
                    s_prefix = (prefix12 << 8) | (unsigned)(255 - 4 * tid - m);
                }
                run += c[m];
            }
        }
        __syncthreads();
        const unsigned T20 = s_prefix;               // k-th key's 20-bit prefix
        const unsigned B_lo = T20 << 12, B_hi = (T20 << 12) | 0xFFFu;

        // ---- Error band: [B_lo - SLOP, B_hi + SLOP]. key > hi => certainly top-k;
        // key < lo => certainly not; band resolved exactly in f64 below.
        lo_thr = (B_lo > SLOP) ? B_lo - SLOP : 1u;   // >=1 excludes w<=0 sentinels
        hi_thr = B_hi + SLOP;                        // no overflow (keys <= 0x7F800000)
        unsigned nhi = 0;
        #pragma unroll
        for (int e = 0; e < 4; ++e) {
            if (key[e] > hi_thr) {
                nhi++;
            } else if (key[e] >= lo_thr) {
                unsigned pos = atomicAdd(&s_bn, 1u);
                if (pos < BCAP) {
                    double t = -log((double)uv[e]);
                    double r = (double)fmaxf(wv[e], 1e-30f) / t;   // exact-order key
                    bkey[pos] = (unsigned long long)__double_as_longlong(r);
                    bidx[pos] = 4 * tid + e;
                }
            }
        }
        {
            unsigned nv = nhi;
            #pragma unroll
            for (int off = 32; off > 0; off >>= 1) nv += __shfl_down(nv, off, 64);
            if (lane == 0) s_nhiw[wid] = nv;
        }
        __syncthreads();
        unsigned nhi_tot = 0;
        #pragma unroll
        for (int w2 = 0; w2 < NW; ++w2) nhi_tot += s_nhiw[w2];
        need = k - (int)nhi_tot;                     // >= 1; bn >= need by construction
        bn = s_bn; if (bn > BCAP) bn = BCAP;
    }

    // ---- Phase 3: selection + float32 outputs ----
    const size_t obase = (size_t)row * L_LEN;
    float* o0 = out + obase;                      // masked ids
    float* o1 = out + (size_t)n_per + obase;      // mask
    float* o2 = out + 2 * (size_t)n_per + obase;  // -mask

    float f0[4], f1[4], f2[4];
    #pragma unroll
    for (int e = 0; e < 4; ++e) {
        bool sel;
        if (key[e] > hi_thr) {
            sel = true;
        } else if (key[e] < lo_thr) {
            sel = false;
        } else {
            // band member: rank by (f64 key desc, index asc) — stable, exact
            double t = -log((double)uv[e]);
            double r = (double)fmaxf(wv[e], 1e-30f) / t;
            unsigned long long myk = (unsigned long long)__double_as_longlong(r);
            int myi = 4 * tid + e;
            int rnk = 0;
            for (unsigned j = 0; j < bn; ++j)
                rnk += (bkey[j] > myk) || (bkey[j] == myk && bidx[j] < myi);
            sel = (rnk < need);
        }
        f0[e] = sel ? 103.0f : (float)ida[e];
        f1[e] = sel ? 1.0f : 0.0f;
        f2[e] = sel ? -1.0f : -0.0f;
    }
    reinterpret_cast<float4*>(o0)[tid] = make_float4(f0[0], f0[1], f0[2], f0[3]);
    reinterpret_cast<float4*>(o1)[tid] = make_float4(f1[0], f1[1], f1[2], f1[3]);
    reinterpret_cast<float4*>(o2)[tid] = make_float4(f2[0], f2[1], f2[2], f2[3]);
}

extern "C" void kernel_launch(void* const* d_in, const int* in_sizes, int n_in,
                              void* d_out, int out_size, void* d_ws, size_t ws_size,
                              hipStream_t stream) {
    const int*   ids   = (const int*)d_in[0];     // (B,J,L) ids (int32/int64 auto-detect)
    const float* amask = (const float*)d_in[1];   // (B,J,2L) float32
    const float* uin   = (const float*)d_in[2];   // (B,J,L) float32
    float* out = (float*)d_out;                   // float32 x (3 * B*J*L)

    const int n_per = ROWS * L_LEN;               // 2,097,152 (hardcoded geometry)

    AttentionEssentialReinforce_51238959841470_kernel<<<dim3(ROWS), dim3(NT), 0, stream>>>(
        ids, amask, uin, out, n_per);
}